// Round 1
// baseline (2402.435 us; speedup 1.0000x reference)
//
#include <hip/hip_runtime.h>
#include <cstdint>

#define NBATCH 16
#define NPTS   100000
#define NPOINT 1024
#define GPB    16            // blocks per batch
#define TPB    256           // threads per block
#define STRIDE (GPB * TPB)   // 4096 threads per batch
#define KPT    25            // ceil(NPTS / STRIDE)

// d_ws layout:
//   @0    : float  sums[16][4]      (256 B)  — batch coordinate sums (atomicAdd)
//   @256  : uint   maxbits[16]      (64 B)   — batch max squared radius, float bits (atomicMax)
//   @4096 : u64    slots[2][256]    (4096 B) — per-(parity,batch,block) argmax message
// memset(d_ws, 0, 8192) before launch (harness poisons with 0xAA).

// ---------------- precompute: per-batch coordinate sums ----------------
__global__ __launch_bounds__(256) void sum_kernel(const float* __restrict__ xyz,
                                                  float* __restrict__ sums) {
    const int b   = blockIdx.x & 15;
    const int sub = blockIdx.x >> 4;      // 8 blocks per batch
    const float* P = xyz + (size_t)b * NPTS * 3;
    float sx = 0.f, sy = 0.f, sz = 0.f;
    for (int i = sub * TPB + threadIdx.x; i < NPTS; i += 8 * TPB) {
        sx += P[i * 3 + 0];
        sy += P[i * 3 + 1];
        sz += P[i * 3 + 2];
    }
    #pragma unroll
    for (int off = 32; off; off >>= 1) {
        sx += __shfl_xor(sx, off);
        sy += __shfl_xor(sy, off);
        sz += __shfl_xor(sz, off);
    }
    __shared__ float r[3][4];
    const int wave = threadIdx.x >> 6, lane = threadIdx.x & 63;
    if (lane == 0) { r[0][wave] = sx; r[1][wave] = sy; r[2][wave] = sz; }
    __syncthreads();
    if (threadIdx.x == 0) {
        atomicAdd(&sums[b * 4 + 0], r[0][0] + r[0][1] + r[0][2] + r[0][3]);
        atomicAdd(&sums[b * 4 + 1], r[1][0] + r[1][1] + r[1][2] + r[1][3]);
        atomicAdd(&sums[b * 4 + 2], r[2][0] + r[2][1] + r[2][2] + r[2][3]);
    }
}

// ---------------- precompute: per-batch max squared radius ----------------
__global__ __launch_bounds__(256) void max_kernel(const float* __restrict__ xyz,
                                                  const float* __restrict__ sums,
                                                  unsigned* __restrict__ maxbits) {
    const int b   = blockIdx.x & 15;
    const int sub = blockIdx.x >> 4;
    const float* P = xyz + (size_t)b * NPTS * 3;
    const float mx = sums[b * 4 + 0] / (float)NPTS;
    const float my = sums[b * 4 + 1] / (float)NPTS;
    const float mz = sums[b * 4 + 2] / (float)NPTS;
    float best = 0.f;
    for (int i = sub * TPB + threadIdx.x; i < NPTS; i += 8 * TPB) {
        float dx = P[i * 3 + 0] - mx;
        float dy = P[i * 3 + 1] - my;
        float dz = P[i * 3 + 2] - mz;
        float d = dx * dx + dy * dy + dz * dz;
        best = fmaxf(best, d);
    }
    #pragma unroll
    for (int off = 32; off; off >>= 1) best = fmaxf(best, __shfl_xor(best, off));
    __shared__ float r[4];
    const int wave = threadIdx.x >> 6, lane = threadIdx.x & 63;
    if (lane == 0) r[wave] = best;
    __syncthreads();
    if (threadIdx.x == 0) {
        float m = fmaxf(fmaxf(r[0], r[1]), fmaxf(r[2], r[3]));
        atomicMax(&maxbits[b], __float_as_uint(m));  // d >= 0 -> bits are order-preserving
    }
}

// ---------------- main: farthest point sampling + fused gather/normalize ----------------
// Message word: [63:54] = seq (iteration+1), [53:22] = float bits of max distance (>=0),
//               [21:0]  = 0x3FFFFF - point_index  (max-compare => smallest index on ties,
//                         matching np.argmax first-occurrence)
__global__ __launch_bounds__(256) void fps_kernel(const float* __restrict__ xyz,
                                                  const float* __restrict__ cmap,
                                                  const int* __restrict__ init_far,
                                                  const unsigned* __restrict__ maxbits,
                                                  unsigned long long* __restrict__ slots,
                                                  float* __restrict__ out) {
    const int b   = blockIdx.x & 15;   // batch: blocks of a batch land on one XCD (i % 8)
    const int g   = blockIdx.x >> 4;   // block-in-batch 0..15
    const int tid = threadIdx.x;
    const int tl  = g * TPB + tid;     // batch-local lane 0..4095
    const float* P = xyz + (size_t)b * NPTS * 3;

    // register-resident points + running distances
    float px[KPT], py[KPT], pz[KPT], pd[KPT];
    #pragma unroll
    for (int k = 0; k < KPT; ++k) {
        const int p = tl + k * STRIDE;
        const bool v = p < NPTS;
        px[k] = v ? P[p * 3 + 0] : 0.f;
        py[k] = v ? P[p * 3 + 1] : 0.f;
        pz[k] = v ? P[p * 3 + 2] : 0.f;
        pd[k] = v ? 1e10f : -1.0f;     // masked slots can never win the argmax (real d >= 0)
    }

    __shared__ unsigned long long lds_key[4];
    __shared__ int lds_win;
    const int wave = tid >> 6, lane = tid & 63;

    int cur = init_far[b];
    const float sb = sqrtf(__uint_as_float(maxbits[b]));
    const bool writer = (g == 0) && (tid == 0);

    for (int i = 0; i < NPOINT; ++i) {
        // centroid coords: same address across the wave -> broadcast load (L2-hot)
        const float cx = P[cur * 3 + 0];
        const float cy = P[cur * 3 + 1];
        const float cz = P[cur * 3 + 2];

        if (writer) {
            const float c = cmap[(size_t)b * NPTS + cur];
            float* o = out + ((size_t)b * NPOINT + i) * 4;
            o[0] = c;
            o[1] = cx / sb;
            o[2] = cy / sb;
            o[3] = cz / sb;
        }
        if (i == NPOINT - 1) break;

        // min-update + per-thread argmax (exact fp order match with numpy: no fma)
        float best = -1.0f;
        int bestk = 0;
        {
            #pragma clang fp contract(off)
            #pragma unroll
            for (int k = 0; k < KPT; ++k) {
                float dx = px[k] - cx;
                float dy = py[k] - cy;
                float dz = pz[k] - cz;
                float dist = dx * dx + dy * dy;
                dist = dist + dz * dz;
                float nd = fminf(pd[k], dist);
                pd[k] = nd;
                if (nd > best) { best = nd; bestk = k; }  // strict > keeps smallest k
            }
        }
        const unsigned pidx = (unsigned)(tl + bestk * STRIDE);
        unsigned long long key =
            ((unsigned long long)__float_as_uint(best) << 22) |
            (unsigned long long)(0x3FFFFFu - pidx);

        // wave argmax
        #pragma unroll
        for (int off = 32; off; off >>= 1) {
            unsigned long long o2 = __shfl_xor(key, off);
            key = o2 > key ? o2 : key;
        }
        if (lane == 0) lds_key[wave] = key;
        __syncthreads();   // syncA

        if (wave == 0) {
            unsigned long long kb = lds_key[0];
            kb = lds_key[1] > kb ? lds_key[1] : kb;
            kb = lds_key[2] > kb ? lds_key[2] : kb;
            kb = lds_key[3] > kb ? lds_key[3] : kb;
            const unsigned long long send = kb | ((unsigned long long)(i + 1) << 54);
            if (lane == 0)
                __hip_atomic_store(&slots[(i & 1) * 256 + b * GPB + g], send,
                                   __ATOMIC_RELAXED, __HIP_MEMORY_SCOPE_AGENT);
            // poll the 16 peer slots (lanes 0..15, one slot each)
            unsigned long long v = 0;
            if (lane < GPB) {
                unsigned long long* sp = &slots[(i & 1) * 256 + b * GPB + lane];
                const unsigned long long want = (unsigned long long)(i + 1);
                for (;;) {
                    v = __hip_atomic_load(sp, __ATOMIC_RELAXED, __HIP_MEMORY_SCOPE_AGENT);
                    if ((v >> 54) >= want) break;   // == under the lag<=1 handshake proof
                    __builtin_amdgcn_s_sleep(1);
                }
            }
            #pragma unroll
            for (int off = 8; off; off >>= 1) {
                unsigned long long o2 = __shfl_xor(v, off);
                v = o2 > v ? o2 : v;
            }
            if (lane == 0)
                lds_win = (int)(0x3FFFFFu - (unsigned)(v & 0x3FFFFFu));
        }
        __syncthreads();   // syncB
        cur = lds_win;
    }
}

extern "C" void kernel_launch(void* const* d_in, const int* in_sizes, int n_in,
                              void* d_out, int out_size, void* d_ws, size_t ws_size,
                              hipStream_t stream) {
    const float* mesh = (const float*)d_in[0];
    const float* cmap = (const float*)d_in[1];
    const int* init   = (const int*)d_in[2];
    // d_in[3] = npoint scalar (fixed 1024, compiled in)
    float* out = (float*)d_out;

    char* ws = (char*)d_ws;
    float* sums                 = (float*)ws;
    unsigned* maxbits           = (unsigned*)(ws + 256);
    unsigned long long* slots   = (unsigned long long*)(ws + 4096);

    hipMemsetAsync(d_ws, 0, 8192, stream);
    sum_kernel<<<dim3(128), dim3(TPB), 0, stream>>>(mesh, sums);
    max_kernel<<<dim3(128), dim3(TPB), 0, stream>>>(mesh, sums, maxbits);
    fps_kernel<<<dim3(256), dim3(TPB), 0, stream>>>(mesh, cmap, init, maxbits, slots, out);
}